// Round 7
// baseline (45.711 us; speedup 1.0000x reference)
//
#include <hip/hip_runtime.h>
#include <hip/hip_cooperative_groups.h>

namespace cg = cooperative_groups;

// TripletHardLoss — round-3 verified kernel body, single COOPERATIVE dispatch:
// tile blocks write partials, grid.sync(), block 0 does the fixed-order final
// reduce. Removes the second graph node + inter-node gap.
// Math: a' = a + eps;  ||a'_i - b_j||^2 = na[i] + nb[j] - 2 (a'_i . b_j).
// Gram via bf16 MFMA (absmax 0 measured vs 2.3e-2 threshold); norms and all
// diagonal distances in exact fp32.

#define EPSV 1e-6f
#define MARGINV 1.0f

typedef float  v4f  __attribute__((ext_vector_type(4)));
typedef short  s8v  __attribute__((ext_vector_type(8)));

constexpr int BB = 512;
constexpr int DD = 256;
constexpr int D4 = DD / 4;       // 64 float4 per row
constexpr int TT = 32;           // 32x32 output tile per block
constexpr int NB = BB / TT;      // 16
constexpr int NBLK = NB * NB;    // 256 blocks (1 per CU)
constexpr float INV_N = 1.0f / (513.0f * 512.0f);

__device__ __forceinline__ unsigned short f2bf(float f) {
    unsigned int u = __float_as_uint(f);
    unsigned int r = (u + 0x7FFFu + ((u >> 16) & 1u)) >> 16;   // RNE
    return (unsigned short)r;
}
__device__ __forceinline__ unsigned int pk(float x, float y) {
    return (unsigned int)f2bf(x) | ((unsigned int)f2bf(y) << 16);
}

__global__ void __launch_bounds__(256) triplet_coop_kernel(
    const float* __restrict__ a, const float* __restrict__ b,
    const float* __restrict__ c, const float* __restrict__ d,
    float* __restrict__ partial, float* __restrict__ out)
{
    __shared__ __align__(16) unsigned short sA[TT * DD];  // bf16 a' tile, swizzled
    __shared__ __align__(16) unsigned short sB[TT * DD];  // bf16 b  tile, swizzled
    __shared__ float sNa[TT], sNb[TT], sDap[TT], sDac[TT], sDad[TT];
    __shared__ float sRed[4];

    const int t  = threadIdx.x;
    const int bi = blockIdx.x >> 4;       // / NB
    const int bj = blockIdx.x & (NB - 1);
    const int i0 = bi * TT;
    const int j0 = bj * TT;

    // ---- stage a' and b tiles -> bf16 LDS (XOR-swizzled 16B slots) --------
    {
        const float4* a4 = (const float4*)a;
        const float4* b4 = (const float4*)b;
        #pragma unroll
        for (int kk = 0; kk < 8; ++kk) {
            int idx  = t + kk * 256;
            int row  = idx >> 6;          // 0..31
            int col4 = idx & 63;          // float4 column
            int sw   = (row & 7) << 3;    // ushort-index XOR = byte XOR <<4

            float4 av = a4[(i0 + row) * D4 + col4];
            av.x += EPSV; av.y += EPSV; av.z += EPSV; av.w += EPSV;
            *(uint2*)&sA[(row * DD + col4 * 4) ^ sw] =
                make_uint2(pk(av.x, av.y), pk(av.z, av.w));

            float4 bv = b4[(j0 + row) * D4 + col4];
            *(uint2*)&sB[(row * DD + col4 * 4) ^ sw] =
                make_uint2(pk(bv.x, bv.y), pk(bv.z, bv.w));
        }
    }

    // ---- fp32 row norms + diagonal distances (L1-hit re-reads) -------------
    {
        const int row = t >> 3, seg = t & 7;
        const float4* a4 = (const float4*)a;
        const float4* b4 = (const float4*)b;
        float na = 0.f, nb = 0.f, dap = 0.f;
        #pragma unroll
        for (int q = 0; q < 8; ++q) {
            int c4 = seg + q * 8;
            float4 av = a4[(i0 + row) * D4 + c4];
            av.x += EPSV; av.y += EPSV; av.z += EPSV; av.w += EPSV;
            float4 bjv = b4[(j0 + row) * D4 + c4];
            float4 biv = b4[(i0 + row) * D4 + c4];
            na += av.x * av.x + av.y * av.y + av.z * av.z + av.w * av.w;
            nb += bjv.x * bjv.x + bjv.y * bjv.y + bjv.z * bjv.z + bjv.w * bjv.w;
            float e0 = av.x - biv.x, e1 = av.y - biv.y;
            float e2 = av.z - biv.z, e3 = av.w - biv.w;
            dap += e0 * e0 + e1 * e1 + e2 * e2 + e3 * e3;
        }
        #pragma unroll
        for (int off = 4; off; off >>= 1) {
            na  += __shfl_down(na,  off, 8);
            nb  += __shfl_down(nb,  off, 8);
            dap += __shfl_down(dap, off, 8);
        }
        if (seg == 0) { sNa[row] = na; sNb[row] = nb; sDap[row] = sqrtf(dap); }

        if (bj == 0) {   // bj==0 blocks own the c/d terms for their 32 rows
            const float4* c4p = (const float4*)c;
            const float4* d4p = (const float4*)d;
            float dac = 0.f, dad = 0.f;
            #pragma unroll
            for (int q = 0; q < 8; ++q) {
                int c4 = seg + q * 8;
                float4 av = a4[(i0 + row) * D4 + c4];
                av.x += EPSV; av.y += EPSV; av.z += EPSV; av.w += EPSV;
                float4 cv = c4p[(i0 + row) * D4 + c4];
                float4 dv = d4p[(i0 + row) * D4 + c4];
                float e0 = av.x - cv.x, e1 = av.y - cv.y;
                float e2 = av.z - cv.z, e3 = av.w - cv.w;
                dac += e0 * e0 + e1 * e1 + e2 * e2 + e3 * e3;
                e0 = av.x - dv.x; e1 = av.y - dv.y;
                e2 = av.z - dv.z; e3 = av.w - dv.w;
                dad += e0 * e0 + e1 * e1 + e2 * e2 + e3 * e3;
            }
            #pragma unroll
            for (int off = 4; off; off >>= 1) {
                dac += __shfl_down(dac, off, 8);
                dad += __shfl_down(dad, off, 8);
            }
            if (seg == 0) { sDac[row] = sqrtf(dac); sDad[row] = sqrtf(dad); }
        }
    }
    __syncthreads();

    // ---- MFMA: G = A' * B^T for the 32x32 tile -----------------------------
    const int l  = t & 63, w = t >> 6;
    const int wi = w >> 1, wj = w & 1;
    const int arow = wi * 16 + (l & 15);
    const int brow = wj * 16 + (l & 15);
    const int asw = (arow & 7) << 3;
    const int bsw = (brow & 7) << 3;
    const int kbase = (l >> 4) * 8;

    v4f acc = {0.f, 0.f, 0.f, 0.f};
    #pragma unroll
    for (int kc = 0; kc < 8; ++kc) {
        int k0 = kc * 32 + kbase;
        s8v af = *(const s8v*)&sA[(arow * DD + k0) ^ asw];
        s8v bf = *(const s8v*)&sB[(brow * DD + k0) ^ bsw];
        acc = __builtin_amdgcn_mfma_f32_16x16x32_bf16(af, bf, acc, 0, 0, 0);
    }

    // ---- epilogue: distances + relu terms ----------------------------------
    // C/D layout: col = lane&15, row = (lane>>4)*4 + reg
    float s = 0.f;
    const int jl = wj * 16 + (l & 15);
    const int jg = j0 + jl;
    const float nbj = sNb[jl];
    #pragma unroll
    for (int r = 0; r < 4; ++r) {
        int il = wi * 16 + (l >> 4) * 4 + r;
        int ig = i0 + il;
        float D2 = sNa[il] + nbj - 2.0f * acc[r];
        float dist = sqrtf(fmaxf(D2, 0.f));
        if (ig != jg) s += fmaxf(sDap[il] - dist + MARGINV, 0.f);
    }
    if (bj == 0 && t < TT) {
        s += fmaxf(sDap[t] - sDac[t] + MARGINV, 0.f);
        s += fmaxf(sDap[t] - sDad[t] + MARGINV, 0.f);
    }

    // ---- deterministic block reduction -> one partial per block ------------
    #pragma unroll
    for (int off = 32; off; off >>= 1) s += __shfl_down(s, off);
    if (l == 0) sRed[w] = s;
    __syncthreads();
    if (t == 0) partial[blockIdx.x] = ((sRed[0] + sRed[1]) + sRed[2]) + sRed[3];

    // ---- grid barrier, then block 0 does the fixed-order final sum ---------
    cg::this_grid().sync();

    if (blockIdx.x == 0 && t < 64) {
        float x0 = partial[t];
        float x1 = partial[t + 64];
        float x2 = partial[t + 128];
        float x3 = partial[t + 192];
        float x = ((x0 + x1) + x2) + x3;
        #pragma unroll
        for (int off = 32; off; off >>= 1) x += __shfl_down(x, off);
        if (t == 0) out[0] = x * INV_N;
    }
}

extern "C" void kernel_launch(void* const* d_in, const int* in_sizes, int n_in,
                              void* d_out, int out_size, void* d_ws, size_t ws_size,
                              hipStream_t stream) {
    const float* a = (const float*)d_in[0];
    const float* b = (const float*)d_in[1];
    const float* c = (const float*)d_in[2];
    const float* d = (const float*)d_in[3];
    float* partial = (float*)d_ws;               // 256 floats
    float* outp    = (float*)d_out;

    void* args[] = { (void*)&a, (void*)&b, (void*)&c, (void*)&d,
                     (void*)&partial, (void*)&outp };
    hipLaunchCooperativeKernel((const void*)triplet_coop_kernel,
                               dim3(NBLK), dim3(256), args, 0, stream);
}

// Round 8
// 11.467 us; speedup vs baseline: 3.9864x; 3.9864x over previous
//
#include <hip/hip_runtime.h>

// TripletHardLoss — round-3 verified two-dispatch structure (best measured:
// 11.55 us). Single local change: c-diag owned by bj==1 blocks, d-diag by
// bj==2 (was: both on bj==0) to halve the straggler block's extra work.
// Math: a' = a + eps;  ||a'_i - b_j||^2 = na[i] + nb[j] - 2 (a'_i . b_j).
// Gram via bf16 MFMA (absmax 0 measured vs 2.3e-2 threshold); norms and all
// diagonal distances in exact fp32.

#define EPSV 1e-6f
#define MARGINV 1.0f

typedef float  v4f  __attribute__((ext_vector_type(4)));
typedef short  s8v  __attribute__((ext_vector_type(8)));

constexpr int BB = 512;
constexpr int DD = 256;
constexpr int D4 = DD / 4;       // 64 float4 per row
constexpr int TT = 32;           // 32x32 output tile per block
constexpr int NB = BB / TT;      // 16
constexpr int NBLK = NB * NB;    // 256 blocks (1 per CU)
constexpr float INV_N = 1.0f / (513.0f * 512.0f);

__device__ __forceinline__ unsigned short f2bf(float f) {
    unsigned int u = __float_as_uint(f);
    unsigned int r = (u + 0x7FFFu + ((u >> 16) & 1u)) >> 16;   // RNE
    return (unsigned short)r;
}
__device__ __forceinline__ unsigned int pk(float x, float y) {
    return (unsigned int)f2bf(x) | ((unsigned int)f2bf(y) << 16);
}

__global__ void __launch_bounds__(256) triplet_tile_kernel(
    const float* __restrict__ a, const float* __restrict__ b,
    const float* __restrict__ c, const float* __restrict__ d,
    float* __restrict__ partial)
{
    __shared__ __align__(16) unsigned short sA[TT * DD];  // bf16 a' tile, swizzled
    __shared__ __align__(16) unsigned short sB[TT * DD];  // bf16 b  tile, swizzled
    __shared__ float sNa[TT], sNb[TT], sDap[TT], sDae[TT];
    __shared__ float sRed[4];

    const int t  = threadIdx.x;
    const int bi = blockIdx.x >> 4;       // / NB
    const int bj = blockIdx.x & (NB - 1);
    const int i0 = bi * TT;
    const int j0 = bj * TT;

    // ---- stage a' and b tiles -> bf16 LDS (XOR-swizzled 16B slots) --------
    // 32 rows x 64 float4 per tile; 8 float4 per thread, wave = 1 KB contig.
    {
        const float4* a4 = (const float4*)a;
        const float4* b4 = (const float4*)b;
        #pragma unroll
        for (int kk = 0; kk < 8; ++kk) {
            int idx  = t + kk * 256;
            int row  = idx >> 6;          // 0..31
            int col4 = idx & 63;          // float4 column
            int sw   = (row & 7) << 3;    // ushort-index XOR = byte XOR <<4

            float4 av = a4[(i0 + row) * D4 + col4];
            av.x += EPSV; av.y += EPSV; av.z += EPSV; av.w += EPSV;
            *(uint2*)&sA[(row * DD + col4 * 4) ^ sw] =
                make_uint2(pk(av.x, av.y), pk(av.z, av.w));

            float4 bv = b4[(j0 + row) * D4 + col4];
            *(uint2*)&sB[(row * DD + col4 * 4) ^ sw] =
                make_uint2(pk(bv.x, bv.y), pk(bv.z, bv.w));
        }
    }

    // ---- fp32 row norms + diagonal distances (L1-hit re-reads) -------------
    // row = t>>3 (0..31), seg = t&7; 8 lanes cover one row (128B chunks).
    {
        const int row = t >> 3, seg = t & 7;
        const float4* a4 = (const float4*)a;
        const float4* b4 = (const float4*)b;
        float na = 0.f, nb = 0.f, dap = 0.f;
        #pragma unroll
        for (int q = 0; q < 8; ++q) {
            int c4 = seg + q * 8;
            float4 av = a4[(i0 + row) * D4 + c4];
            av.x += EPSV; av.y += EPSV; av.z += EPSV; av.w += EPSV;
            float4 bjv = b4[(j0 + row) * D4 + c4];
            float4 biv = b4[(i0 + row) * D4 + c4];
            na += av.x * av.x + av.y * av.y + av.z * av.z + av.w * av.w;
            nb += bjv.x * bjv.x + bjv.y * bjv.y + bjv.z * bjv.z + bjv.w * bjv.w;
            float e0 = av.x - biv.x, e1 = av.y - biv.y;
            float e2 = av.z - biv.z, e3 = av.w - biv.w;
            dap += e0 * e0 + e1 * e1 + e2 * e2 + e3 * e3;
        }
        #pragma unroll
        for (int off = 4; off; off >>= 1) {
            na  += __shfl_down(na,  off, 8);
            nb  += __shfl_down(nb,  off, 8);
            dap += __shfl_down(dap, off, 8);
        }
        if (seg == 0) { sNa[row] = na; sNb[row] = nb; sDap[row] = sqrtf(dap); }

        // c-diag owned by bj==1 blocks, d-diag by bj==2 (straggler balance)
        if (bj == 1 || bj == 2) {
            const float4* e4 = (const float4*)((bj == 1) ? c : d);
            float dae = 0.f;
            #pragma unroll
            for (int q = 0; q < 8; ++q) {
                int c4 = seg + q * 8;
                float4 av = a4[(i0 + row) * D4 + c4];
                av.x += EPSV; av.y += EPSV; av.z += EPSV; av.w += EPSV;
                float4 ev = e4[(i0 + row) * D4 + c4];
                float f0 = av.x - ev.x, f1 = av.y - ev.y;
                float f2 = av.z - ev.z, f3 = av.w - ev.w;
                dae += f0 * f0 + f1 * f1 + f2 * f2 + f3 * f3;
            }
            #pragma unroll
            for (int off = 4; off; off >>= 1) dae += __shfl_down(dae, off, 8);
            if (seg == 0) sDae[row] = sqrtf(dae);
        }
    }
    __syncthreads();

    // ---- MFMA: G = A' * B^T for the 32x32 tile -----------------------------
    // wave w -> 16x16 sub-tile (wi = w>>1, wj = w&1).
    const int l  = t & 63, w = t >> 6;
    const int wi = w >> 1, wj = w & 1;
    const int arow = wi * 16 + (l & 15);
    const int brow = wj * 16 + (l & 15);
    const int asw = (arow & 7) << 3;
    const int bsw = (brow & 7) << 3;
    const int kbase = (l >> 4) * 8;

    v4f acc = {0.f, 0.f, 0.f, 0.f};
    #pragma unroll
    for (int kc = 0; kc < 8; ++kc) {
        int k0 = kc * 32 + kbase;
        s8v af = *(const s8v*)&sA[(arow * DD + k0) ^ asw];
        s8v bf = *(const s8v*)&sB[(brow * DD + k0) ^ bsw];
        acc = __builtin_amdgcn_mfma_f32_16x16x32_bf16(af, bf, acc, 0, 0, 0);
    }

    // ---- epilogue: distances + relu terms ----------------------------------
    // C/D layout: col = lane&15, row = (lane>>4)*4 + reg   [verified]
    float s = 0.f;
    const int jl = wj * 16 + (l & 15);
    const int jg = j0 + jl;
    const float nbj = sNb[jl];
    #pragma unroll
    for (int r = 0; r < 4; ++r) {
        int il = wi * 16 + (l >> 4) * 4 + r;
        int ig = i0 + il;
        float D2 = sNa[il] + nbj - 2.0f * acc[r];
        float dist = sqrtf(fmaxf(D2, 0.f));
        if (ig != jg) s += fmaxf(sDap[il] - dist + MARGINV, 0.f);
    }
    if ((bj == 1 || bj == 2) && t < TT) {
        s += fmaxf(sDap[t] - sDae[t] + MARGINV, 0.f);
    }

    // ---- deterministic block reduction -> one partial per block ------------
    #pragma unroll
    for (int off = 32; off; off >>= 1) s += __shfl_down(s, off);
    if (l == 0) sRed[w] = s;
    __syncthreads();
    if (t == 0) partial[blockIdx.x] = ((sRed[0] + sRed[1]) + sRed[2]) + sRed[3];
}

// ---------------------------------------------------------------------------
// Final deterministic fixed-order sum of the 256 partials.
__global__ void __launch_bounds__(64) triplet_reduce_kernel(
    const float* __restrict__ partial, float* __restrict__ out)
{
    int t = threadIdx.x;
    float x0 = partial[t];
    float x1 = partial[t + 64];
    float x2 = partial[t + 128];
    float x3 = partial[t + 192];
    float x = ((x0 + x1) + x2) + x3;
    #pragma unroll
    for (int off = 32; off; off >>= 1) x += __shfl_down(x, off);
    if (t == 0) out[0] = x * INV_N;
}

extern "C" void kernel_launch(void* const* d_in, const int* in_sizes, int n_in,
                              void* d_out, int out_size, void* d_ws, size_t ws_size,
                              hipStream_t stream) {
    const float* a = (const float*)d_in[0];
    const float* b = (const float*)d_in[1];
    const float* c = (const float*)d_in[2];
    const float* d = (const float*)d_in[3];
    float* partial = (float*)d_ws;               // 256 floats

    triplet_tile_kernel<<<NBLK, 256, 0, stream>>>(a, b, c, d, partial);
    triplet_reduce_kernel<<<1, 64, 0, stream>>>(partial, (float*)d_out);
}